// Round 1
// baseline (390.275 us; speedup 1.0000x reference)
//
#include <hip/hip_runtime.h>
#include <stdint.h>

// Attention_76459007804089: M=8192 graphs x 64 nodes x 128 dims, fp32.
//   Q = H @ A ; e_i = dot(x_i, q_g) ; att = segment_softmax(exp(e)) ;
//   out[g] = sum_i att_i * x_i
//
// Restructure vs previous version:
//   Kernel 1 (q_gemm): Q = H@A written into `out` (scratch; exactly M*128 fp32).
//     Removes the per-graph 64KB `a` re-read + dependent-FMA chain from the hot loop.
//   Kernel 2 (gat_main): 8 graphs per 256-thread block, double-buffered
//     global_load_lds staging with COUNTED vmcnt (s_waitcnt vmcnt(9)) and raw
//     s_barrier -- prefetch for graph g+1 stays in flight across all barriers of
//     graph g (T3/T4 pattern). __syncthreads is never used in the main loop
//     because the compiler drains vmcnt(0) before it, which was the 374us killer.
//   LDS layout: linear chunks (global_load_lds requirement) with XOR-swizzled
//     SOURCE addresses: LDS 16B-chunk L holds global chunk G = L ^ ((L>>5)&7).
//     Both read phases then XOR the same involution => every wave ds_read_b128
//     lands exactly 8 dword accesses per bank (the 1024B/wave structural floor).

#define NPG   64
#define DDIM  128
#define NG    8      // graphs per block in the main kernel

typedef __attribute__((ext_vector_type(4))) float f32x4;

__device__ __forceinline__ void gld_lds16(const void* g, void* l) {
    __builtin_amdgcn_global_load_lds(
        (const __attribute__((address_space(1))) void*)g,
        (__attribute__((address_space(3))) void*)l,
        16, 0, 0);
}

// ---------------- Kernel 1: Q = H (m x 128) @ A (128 x 128) -> out (scratch) --
__global__ __launch_bounds__(256) void q_gemm(const float* __restrict__ h,
                                              const float* __restrict__ a,
                                              float* __restrict__ q)
{
    const int t    = threadIdx.x;
    const int j    = t & (DDIM - 1);
    const int half = t >> 7;
    const size_t g0 = (size_t)blockIdx.x * 8 + (size_t)half * 4;  // 4 graphs/thread
    const float* hg = h + g0 * DDIM;
    const float* ac = a + j;
    float a0 = 0.f, a1 = 0.f, a2 = 0.f, a3 = 0.f;
    #pragma unroll 8
    for (int k = 0; k < DDIM; ++k) {
        const float av = ac[(size_t)k * DDIM];   // coalesced across j lanes, L1/L2-hot
        a0 += hg[k]          * av;               // h values: wave-uniform broadcasts
        a1 += hg[DDIM   + k] * av;
        a2 += hg[2*DDIM + k] * av;
        a3 += hg[3*DDIM + k] * av;
    }
    q[(g0 + 0) * DDIM + j] = a0;
    q[(g0 + 1) * DDIM + j] = a1;
    q[(g0 + 2) * DDIM + j] = a2;
    q[(g0 + 3) * DDIM + j] = a3;
}

// ---------------- Kernel 2: fused attention, 8 graphs/block, dbuf pipeline ----
__global__ __launch_bounds__(256) void gat_main(const float* __restrict__ x,
                                                const float* qsrc,   // aliases out
                                                float* out)
{
    __shared__ __align__(16) float xs[2][NPG * DDIM];  // 2 x 32 KB, swizzled chunks
    __shared__ __align__(16) float qs[2][DDIM];        // 2 x 512 B
    __shared__ float ep[256];                          // per-(wave,node) e partials

    const int t    = threadIdx.x;
    const int lane = t & 63;
    const int w    = t >> 6;
    const int l5   = lane >> 5;
    const int g0   = blockIdx.x * NG;

    // Stage graph g's x tile (+ its q row) into buffer b. 9 vmem ops per wave:
    // 8x global_load_lds_dwordx4 (x) + 1 (q, lanes 0..31 of EVERY wave -> benign
    // duplicate writes, keeps the per-wave vmcnt count uniform at 9).
    auto stage = [&](int g, int b) {
        const char* xg = (const char*)(x + (size_t)g * (NPG * DDIM));
        #pragma unroll
        for (int it = 0; it < 8; ++it) {
            const int Lbase = (w * 8 + it) * 64;          // wave-uniform LDS chunk base
            const int K     = ((2 * it) & 7) | l5;        // ((L>>5)&7) for this lane
            gld_lds16(xg + (size_t)(Lbase + (lane ^ K)) * 16,     // swizzled SOURCE
                      (char*)&xs[b][0] + (size_t)Lbase * 16);     // linear LDS dest
        }
        if (lane < 32)
            gld_lds16((const char*)(qsrc + (size_t)g * DDIM) + lane * 16,
                      (char*)&qs[b][0]);
    };

    stage(g0, 0);   // prologue: 9 outstanding

    #pragma unroll 1
    for (int gi = 0; gi < NG; ++gi) {
        const int cur = gi & 1;
        const int g   = g0 + gi;

        // Issue next tile BEFORE waiting: HBM always has the next tile queued.
        if (gi + 1 < NG) {
            stage(g0 + gi + 1, cur ^ 1);                  // +9 -> 18 outstanding
            asm volatile("s_waitcnt vmcnt(9)" ::: "memory");  // tile cur done, 9 in flight
        } else {
            asm volatile("s_waitcnt vmcnt(0)" ::: "memory");
        }
        __builtin_amdgcn_s_barrier();                     // (1) all waves staged cur

        // ---- e partials: node i = lane, dims [w*32, w*32+32)
        const float* xb = &xs[cur][0];
        const float* qw = &qs[cur][w * 32];
        const int rowbase = lane * 32 + w * 8;            // chunk base for (i, quarter)
        const int ia7     = lane & 7;
        float acc = 0.f;
        #pragma unroll
        for (int c = 0; c < 8; ++c) {
            // read global chunk (i*32 + w*8 + c) at LDS chunk (... ^ ia7): bank-even
            const f32x4 v = *(const f32x4*)(xb + (size_t)(rowbase + (c ^ ia7)) * 4);
            acc += v[0]*qw[c*4+0] + v[1]*qw[c*4+1] + v[2]*qw[c*4+2] + v[3]*qw[c*4+3];
        }
        ep[t] = acc;                                      // ep[w*64 + lane]
        asm volatile("s_waitcnt lgkmcnt(0)" ::: "memory");
        __builtin_amdgcn_s_barrier();                     // (2) ep visible to all waves

        // ---- softmax over the 64 nodes (every wave redundantly; att in-register)
        const float e  = ep[lane] + ep[64 + lane] + ep[128 + lane] + ep[192 + lane];
        const float ex = expf(e);                         // unstabilized, faithful
        float z = ex;
        #pragma unroll
        for (int m = 32; m >= 1; m >>= 1) z += __shfl_xor(z, m, 64);
        const float att = ex / z;

        // ---- out[j] = sum_i att_i * x[i][j]   (waves 0,1: j = t; full unroll so
        // __shfl(att, i) compiles to v_readlane with literal lane index)
        if (t < DDIM) {
            const int jc = t >> 2, jd = t & 3;
            float o0 = 0.f, o1 = 0.f;
            #pragma unroll
            for (int i = 0; i < NPG; i += 2) {
                const float w0 = __shfl(att, i,     64);
                const float w1 = __shfl(att, i + 1, 64);
                o0 += w0 * xb[(size_t)(((i    ) * 32 + jc) ^ ((i    ) & 7)) * 4 + jd];
                o1 += w1 * xb[(size_t)(((i + 1) * 32 + jc) ^ ((i + 1) & 7)) * 4 + jd];
            }
            out[(size_t)g * DDIM + t] = o0 + o1;
        }
        asm volatile("" ::: "memory");
        __builtin_amdgcn_s_barrier();                     // (3) xs[cur] free for reuse
        asm volatile("" ::: "memory");
    }
}

extern "C" void kernel_launch(void* const* d_in, const int* in_sizes, int n_in,
                              void* d_out, int out_size, void* d_ws, size_t ws_size,
                              hipStream_t stream) {
    const float* h = (const float*)d_in[0];   // (M, 128) fp32
    const float* x = (const float*)d_in[1];   // (N, 128) fp32
    const float* a = (const float*)d_in[2];   // (128, 128) fp32
    // d_in[3] = batch_num_nodes (int32): uniformly 64
    float* out = (float*)d_out;               // (M, 128) fp32; doubles as Q scratch

    const int m = in_sizes[0] / DDIM;         // 8192 graphs
    q_gemm<<<m / 8, 256, 0, stream>>>(h, a, out);          // Q -> out (scratch)
    gat_main<<<m / NG, 256, 0, stream>>>(x, out, out);     // reads q[g], overwrites out[g]
}

// Round 2
// 369.677 us; speedup vs baseline: 1.0557x; 1.0557x over previous
//
#include <hip/hip_runtime.h>
#include <stdint.h>

// Attention_76459007804089: M=8192 graphs x 64 nodes x 128 dims, all fp32.
//   q_g = h[g] @ a ; e_i = dot(x_i, q_g) ; att = segment_softmax(exp(e)) ;
//   out[g] = sum_i att_i * x_i
//
// Structure: one 256-thread block per graph (4 blocks/CU; cross-block overlap
// hides per-block barrier drains). x read from HBM exactly once.
// vs the 374.6us round-0 version:
//   - x tile is loaded into REGISTERS first; q = h@a is computed while those
//     8 global loads are in flight (h is read via wave-uniform scalar loads,
//     so no barrier is needed before the q phase). The x->LDS spill happens
//     after, so the compiler's vmcnt wait lands ~500+ cycles after issue.
//   - hq / qpart LDS round-trips removed: both thread-halves compute q
//     redundantly from L2-resident `a` (64KB extra L2 reads/block, ~free),
//     eliminating 2 barriers (6 -> 4).
//   - __launch_bounds__(256,4) pins VGPR<=128 so LDS (36.5KB) stays the
//     occupancy limiter at 4 blocks/CU.

#define NPG  64    // nodes per graph (batch_num_nodes is uniformly 64)
#define DDIM 128   // d_h == d_x
#define SROW 132   // padded LDS row stride in floats (528 B, 16B-aligned, breaks pow2)

typedef __attribute__((ext_vector_type(4))) float f32x4;

__global__ __launch_bounds__(256, 4) void gat_softmax_kernel(
    const float* __restrict__ h,
    const float* __restrict__ x,
    const float* __restrict__ a,
    float* __restrict__ out)
{
    const int g = blockIdx.x;
    const int t = threadIdx.x;

    __shared__ __align__(16) float xs[NPG * SROW];   // 33792 B padded x-tile
    __shared__ float q[DDIM];
    __shared__ __align__(16) float epart[256];
    __shared__ float att[NPG];
    __shared__ float opart[2][DDIM];

    // ---- Phase A-issue: 8 f32x4 coalesced loads of this graph's x tile -> regs
    const f32x4* xg = reinterpret_cast<const f32x4*>(x + (size_t)g * (NPG * DDIM));
    f32x4 xv[8];
    #pragma unroll
    for (int it = 0; it < 8; ++it)
        xv[it] = xg[it * 256 + t];

    // ---- Phase B: q[j] = sum_k h[g][k] * a[k][j], overlapped with x in flight.
    // j = t&127; both thread-halves compute identical sums (no reduction barrier).
    // h row: wave-uniform address -> scalar loads; a: coalesced, L2-resident.
    {
        const int j = t & (DDIM - 1);
        const float* hrow = h + (size_t)g * DDIM;
        const float* ap   = a + j;
        float a0 = 0.f, a1 = 0.f, a2 = 0.f, a3 = 0.f;
        #pragma unroll 8
        for (int k = 0; k < DDIM; k += 4) {
            a0 += hrow[k + 0] * ap[(size_t)(k + 0) * DDIM];
            a1 += hrow[k + 1] * ap[(size_t)(k + 1) * DDIM];
            a2 += hrow[k + 2] * ap[(size_t)(k + 2) * DDIM];
            a3 += hrow[k + 3] * ap[(size_t)(k + 3) * DDIM];
        }
        if (t < DDIM) q[j] = (a0 + a1) + (a2 + a3);
    }

    // ---- Phase A-write: spill x regs to padded LDS, then the first barrier.
    #pragma unroll
    for (int it = 0; it < 8; ++it) {
        const int c   = it * 256 + t;    // chunk id; 32 float4-chunks per row
        const int row = c >> 5;
        const int col = c & 31;
        *reinterpret_cast<f32x4*>(&xs[row * SROW + col * 4]) = xv[it];
    }
    __syncthreads();                                  // (1) xs + q visible

    // ---- Phase C: e partials. thread -> (node i = t/4, quarter = t&3, 32 dims)
    {
        const int i       = t >> 2;
        const int quarter = t & 3;
        const float* xrow = &xs[i * SROW + quarter * 32];
        const float* qq   = &q[quarter * 32];
        float acc = 0.f;
        #pragma unroll
        for (int c = 0; c < 8; ++c) {
            f32x4 v = *reinterpret_cast<const f32x4*>(xrow + c * 4);   // 16B-aligned
            acc += v[0] * qq[c*4] + v[1] * qq[c*4+1] + v[2] * qq[c*4+2] + v[3] * qq[c*4+3];
        }
        epart[t] = acc;
    }
    __syncthreads();                                  // (2) epart visible

    // ---- Softmax over the 64 nodes (wave 0 only; full 64-lane butterfly)
    if (t < NPG) {
        f32x4 p = *reinterpret_cast<const f32x4*>(&epart[4 * t]);
        float e  = p[0] + p[1] + p[2] + p[3];
        float ex = expf(e);               // unstabilized, faithful to reference
        float z  = ex;
        #pragma unroll
        for (int m = 32; m >= 1; m >>= 1)
            z += __shfl_xor(z, m, 64);
        att[t] = ex / z;
    }
    __syncthreads();                                  // (3) att visible

    // ---- Phase D: out[j] = sum_i att_i * xs[i][j]
    // thread -> (dim j = t&127, node half grp = t>>7); lane-consecutive j => 2-way LDS (free)
    {
        const int j   = t & (DDIM - 1);
        const int grp = t >> 7;
        float acc = 0.f;
        #pragma unroll
        for (int k = 0; k < 32; ++k) {
            const int i = grp * 32 + k;
            acc += att[i] * xs[i * SROW + j];   // att[i]: wave-uniform broadcast
        }
        opart[grp][j] = acc;
    }
    __syncthreads();                                  // (4) opart visible

    if (t < DDIM)
        out[(size_t)g * DDIM + t] = opart[0][t] + opart[1][t];
}

extern "C" void kernel_launch(void* const* d_in, const int* in_sizes, int n_in,
                              void* d_out, int out_size, void* d_ws, size_t ws_size,
                              hipStream_t stream) {
    const float* h = (const float*)d_in[0];   // (M, 128) fp32
    const float* x = (const float*)d_in[1];   // (N, 128) fp32
    const float* a = (const float*)d_in[2];   // (128, 128) fp32
    // d_in[3] = batch_num_nodes (int32): uniformly 64 -> node n maps to graph n/64
    float* out = (float*)d_out;               // (M, 128) fp32

    const int m = in_sizes[0] / DDIM;         // 8192 graphs
    gat_softmax_kernel<<<m, 256, 0, stream>>>(h, x, a, out);
}